// Round 5
// baseline (230.882 us; speedup 1.0000x reference)
//
#include <hip/hip_runtime.h>

#define NN 10242

typedef short s8v __attribute__((ext_vector_type(8)));
typedef float f32x4 __attribute__((ext_vector_type(4)));

static __device__ __forceinline__ float bf2f(unsigned short u) {
    unsigned int i = ((unsigned int)u) << 16;
    return __builtin_bit_cast(float, i);
}
static __device__ __forceinline__ unsigned short f2bf(float f) {
    unsigned int i = __builtin_bit_cast(unsigned int, f);
    unsigned int lsb = (i >> 16) & 1u;
    i += 0x7fffu + lsb;
    return (unsigned short)(i >> 16);
}
static __device__ __forceinline__ int imin(int a, int b) { return a < b ? a : b; }

// ---- dtype detector: neigh_weights rows (triples) sum to 1 in the true dtype ----
__global__ void detect_k(const void* __restrict__ wgt, int* __restrict__ flag) {
    const float* wf = (const float*)wgt;
    const int r = threadIdx.x;
    float s = wf[3 * r] + wf[3 * r + 1] + wf[3 * r + 2];
    bool ok = (s == s) && (fabsf(s - 1.f) < 0.05f);
    unsigned long long m = __ballot(ok);
    if (r == 0) *flag = (__popcll(m) >= 60) ? 1 : 0;
}

// ---- canonicalizer ----
// mode 0: ->bf16 (zero-fill i>=nsrc)   mode 1: ->f32   mode 2: W1 cols 75->80 ->bf16
struct Seg { const void* src; void* dst; int n; int nsrc; int mode; };
struct Tab { Seg s[16]; };

__global__ __launch_bounds__(256) void canon_k(Tab t, const int* __restrict__ flag) {
    const Seg sg = t.s[blockIdx.y];
    const bool f32src = (*flag != 0);
    for (int i = blockIdx.x * 256 + threadIdx.x; i < sg.n; i += gridDim.x * 256) {
        if (sg.mode == 0) {
            unsigned short v = 0;
            if (i < sg.nsrc)
                v = f32src ? f2bf(((const float*)sg.src)[i])
                           : ((const unsigned short*)sg.src)[i];
            ((unsigned short*)sg.dst)[i] = v;
        } else if (sg.mode == 1) {
            float v = f32src ? ((const float*)sg.src)[i]
                             : bf2f(((const unsigned short*)sg.src)[i]);
            ((float*)sg.dst)[i] = v;
        } else {
            const int row = i / 80, col = i - row * 80;
            unsigned short v = 0;
            if (col < 75) {
                const int j = row * 75 + col;
                v = f32src ? f2bf(((const float*)sg.src)[j])
                           : ((const unsigned short*)sg.src)[j];
            }
            ((unsigned short*)sg.dst)[i] = v;
        }
    }
}

// ---- layer-1 conv (K=80, VALU; cheap) ----
template<int CIN, int COUT, int CG, int NB>
__global__ __launch_bounds__(256) void conv_k(
    const unsigned short* __restrict__ X,
    const int* __restrict__ idx,
    const float* __restrict__ wgt,
    const unsigned short* __restrict__ W,    // [COUT][KPAD]
    const float* __restrict__ bias,
    float* __restrict__ Of)
{
    constexpr int K = 25 * CIN;
    constexpr int KPAD = (K + 7) & ~7;
    __shared__ unsigned short agg[NB][KPAD];
    const int tid = threadIdx.x;
    const int n0 = blockIdx.x * NB;

    for (int p = tid; p < NB * 25; p += 256) {
        const int r = p / 25;
        const int k = p - r * 25;
        const int n = n0 + r;
        if (n < NN) {
            const int base = n * 75 + k * 3;
            const int i0 = idx[base], i1 = idx[base + 1], i2 = idx[base + 2];
            const float w0 = wgt[base], w1 = wgt[base + 1], w2 = wgt[base + 2];
            for (int e = 0; e < CIN; e++) {
                float v = w0 * bf2f(X[i0 * CIN + e]) +
                          w1 * bf2f(X[i1 * CIN + e]) +
                          w2 * bf2f(X[i2 * CIN + e]);
                agg[r][k * CIN + e] = f2bf(v);
            }
        }
    }
    if constexpr (KPAD != K) {
        for (int p = tid; p < NB * (KPAD - K); p += 256) {
            const int r = p / (KPAD - K);
            agg[r][K + p - r * (KPAD - K)] = 0;
        }
    }
    __syncthreads();

    constexpr int RG = 256 / CG;
    constexpr int RPT = NB / RG;
    const int c = tid % CG;
    const int rq = tid / CG;
    float acc[RPT] = {};
    if (c < COUT) {
        const unsigned short* Wr = W + (size_t)c * KPAD;
        for (int j = 0; j < KPAD; j += 8) {
            s8v wv = *(const s8v*)(Wr + j);
            float wf[8];
            #pragma unroll
            for (int q = 0; q < 8; q++) wf[q] = bf2f((unsigned short)wv[q]);
            #pragma unroll
            for (int rr = 0; rr < RPT; rr++) {
                s8v av = *(const s8v*)(&agg[rq * RPT + rr][j]);
                #pragma unroll
                for (int q = 0; q < 8; q++)
                    acc[rr] += wf[q] * bf2f((unsigned short)av[q]);
            }
        }
        const float bb = bias[c];
        #pragma unroll
        for (int rr = 0; rr < RPT; rr++) {
            const int n = n0 + rq * RPT + rr;
            if (n < NN) Of[(size_t)n * COUT + c] = acc[rr] + bb;
        }
    }
}

// ---- split MFMA conv v2: wave-coalesced gather ----
// Stage 0: idx/wgt -> LDS (coalesced). Stage A: one (node,slot) pair per WAVE,
// lane = channel -> fully coalesced X-row loads, wave-uniform idx/wgt broadcasts.
// Stage B: MFMA from LDS agg; partial[sy] = agg @ W(k-range)^T.
template<int CIN, int COUT, int CPW, int NWB, int MAXS>
__global__ __launch_bounds__(256, 4) void conv2_k(
    const unsigned short* __restrict__ X,    // [N, CIN] bf16
    const int* __restrict__ idx,
    const float* __restrict__ wgt,           // [N*75] f32
    const unsigned short* __restrict__ W,    // [COUTpad][25*CIN] bf16 row-major
    float* __restrict__ partial,             // [S][NN][CSTORE] f32
    int sbase, int srem, int cstore)
{
    constexpr int K = 25 * CIN;
    constexpr int KPAD = MAXS * CIN + 12;    // row stride = MAXS*CIN/2+6 dwords == 6 mod 32
    constexpr int NB = 16;
    __shared__ unsigned short agg[NB][KPAD];
    __shared__ int   iLds[NB][MAXS * 3];
    __shared__ float wLds[NB][MAXS * 3];
    const int tid = threadIdx.x;
    const int n0 = blockIdx.x * NB;
    const int sy = blockIdx.y;
    const int ns = sbase + (sy < srem ? 1 : 0);
    const int s0 = sy * sbase + (sy < srem ? sy : srem);
    const int klocal = ns * CIN;

    // Stage 0: coalesced idx/wgt staging
    const int nf = ns * 3;
    for (int q = tid; q < NB * nf; q += 256) {
        const int r = q / nf, f = q - r * nf;
        const bool ok = (n0 + r) < NN;
        const int g = ok ? ((n0 + r) * 75 + s0 * 3 + f) : 0;
        iLds[r][f] = idx[g];
        wLds[r][f] = ok ? wgt[g] : 0.f;
    }
    __syncthreads();

    // Stage A: pair per wave, lane = channel
    const int wv = tid >> 6;
    const int lane = tid & 63;
    const int npair = NB * ns;
    if constexpr (CIN == 64) {
        for (int p = wv; p < npair; p += 4) {
            const int r = p & 15, kk = p >> 4;
            const int i0 = iLds[r][kk * 3], i1 = iLds[r][kk * 3 + 1], i2 = iLds[r][kk * 3 + 2];
            const float w0 = wLds[r][kk * 3], w1 = wLds[r][kk * 3 + 1], w2 = wLds[r][kk * 3 + 2];
            const float a = bf2f(X[(size_t)i0 * 64 + lane]);
            const float b = bf2f(X[(size_t)i1 * 64 + lane]);
            const float c = bf2f(X[(size_t)i2 * 64 + lane]);
            agg[r][kk * 64 + lane] = f2bf(w0 * a + w1 * b + w2 * c);
        }
    } else {  // CIN == 128: ushort2 per lane
        for (int p = wv; p < npair; p += 4) {
            const int r = p & 15, kk = p >> 4;
            const int i0 = iLds[r][kk * 3], i1 = iLds[r][kk * 3 + 1], i2 = iLds[r][kk * 3 + 2];
            const float w0 = wLds[r][kk * 3], w1 = wLds[r][kk * 3 + 1], w2 = wLds[r][kk * 3 + 2];
            const unsigned int da = *(const unsigned int*)(X + (size_t)i0 * 128 + 2 * lane);
            const unsigned int db = *(const unsigned int*)(X + (size_t)i1 * 128 + 2 * lane);
            const unsigned int dc = *(const unsigned int*)(X + (size_t)i2 * 128 + 2 * lane);
            const float a0 = __builtin_bit_cast(float, da << 16);
            const float a1 = __builtin_bit_cast(float, da & 0xffff0000u);
            const float b0 = __builtin_bit_cast(float, db << 16);
            const float b1 = __builtin_bit_cast(float, db & 0xffff0000u);
            const float c0 = __builtin_bit_cast(float, dc << 16);
            const float c1 = __builtin_bit_cast(float, dc & 0xffff0000u);
            const float v0 = w0 * a0 + w1 * b0 + w2 * c0;
            const float v1 = w0 * a1 + w1 * b1 + w2 * c1;
            *(unsigned int*)(&agg[r][kk * 128 + 2 * lane]) =
                (unsigned int)f2bf(v0) | ((unsigned int)f2bf(v1) << 16);
        }
    }
    __syncthreads();

    // Stage B: MFMA
    if (wv < NWB) {
        constexpr int NFRAG = CPW / 16;
        const int l15 = lane & 15;
        const int kg = lane >> 4;
        f32x4 acc[NFRAG] = {};
        const unsigned short* ap = &agg[l15][kg * 8];
        const unsigned short* wp[NFRAG];
        #pragma unroll
        for (int j = 0; j < NFRAG; j++)
            wp[j] = W + (size_t)(wv * CPW + j * 16 + l15) * K + s0 * CIN + kg * 8;

        #pragma unroll 2
        for (int k0 = 0; k0 < klocal; k0 += 32) {
            s8v a = *(const s8v*)(ap + k0);
            #pragma unroll
            for (int j = 0; j < NFRAG; j++) {
                s8v b = *(const s8v*)(wp[j] + k0);
                acc[j] = __builtin_amdgcn_mfma_f32_16x16x32_bf16(a, b, acc[j], 0, 0, 0);
            }
        }

        #pragma unroll
        for (int j = 0; j < NFRAG; j++) {
            const int col = wv * CPW + j * 16 + l15;
            if (col < COUT) {
                #pragma unroll
                for (int q = 0; q < 4; q++) {
                    const int n = n0 + kg * 4 + q;     // C row = (lane>>4)*4 + reg
                    if (n < NN)
                        partial[((size_t)sy * NN + n) * cstore + col] = acc[j][q];
                }
            }
        }
    }
}

// ---- fused: pre = sum(partials)+bias; column stats partials ----
template<int C, int S>
__global__ __launch_bounds__(256) void reduce_stats_k(
    const float* __restrict__ partial,
    const float* __restrict__ bias,
    float* __restrict__ pre,
    float* __restrict__ part)
{
    constexpr int RG = 256 / C;
    constexpr int CH = (NN + 63) / 64;
    const int b = blockIdx.x;
    const int r0 = b * CH;
    const int r1 = imin(NN, r0 + CH);
    const int c = threadIdx.x % C;
    const int g = threadIdx.x / C;
    const float bb = bias[c];
    float s = 0.f, s2 = 0.f;
    for (int r = r0 + g; r < r1; r += RG) {
        float v = bb;
        #pragma unroll
        for (int si = 0; si < S; si++)
            v += partial[((size_t)si * NN + r) * C + c];
        pre[(size_t)r * C + c] = v;
        s += v; s2 += v * v;
    }
    __shared__ float ls[256], ls2[256];
    ls[threadIdx.x] = s; ls2[threadIdx.x] = s2;
    __syncthreads();
    if (threadIdx.x < C) {
        float a = 0.f, a2 = 0.f;
        #pragma unroll
        for (int g2 = 0; g2 < RG; g2++) {
            a  += ls[g2 * C + threadIdx.x];
            a2 += ls2[g2 * C + threadIdx.x];
        }
        part[b * 2 * C + threadIdx.x] = a;
        part[b * 2 * C + C + threadIdx.x] = a2;
    }
}

// ---- final: out = sum(partials)+bias, store in detected dtype ----
__global__ __launch_bounds__(256) void reduce_out_k(
    const float* __restrict__ partial,
    const float* __restrict__ bias,
    void* __restrict__ Ob,
    const int* __restrict__ flag, int S)
{
    const int i = blockIdx.x * 256 + threadIdx.x;
    if (i >= NN * 36) return;
    const int c = i % 36;
    float v = bias[c];
    for (int si = 0; si < S; si++)
        v += partial[(size_t)si * NN * 36 + i];
    if (*flag) ((float*)Ob)[i] = v;
    else       ((unsigned short*)Ob)[i] = f2bf(v);
}

template<int C>
__global__ __launch_bounds__(256) void stats_k(const float* __restrict__ pre,
                                               float* __restrict__ part)
{
    constexpr int RG = 256 / C;
    constexpr int CH = (NN + 63) / 64;
    const int b = blockIdx.x;
    const int r0 = b * CH;
    const int r1 = imin(NN, r0 + CH);
    const int c = threadIdx.x % C;
    const int g = threadIdx.x / C;
    float s = 0.f, s2 = 0.f;
    for (int r = r0 + g; r < r1; r += RG) {
        float v = pre[(size_t)r * C + c];
        s += v; s2 += v * v;
    }
    __shared__ float ls[256], ls2[256];
    ls[threadIdx.x] = s; ls2[threadIdx.x] = s2;
    __syncthreads();
    if (threadIdx.x < C) {
        float a = 0.f, a2 = 0.f;
        #pragma unroll
        for (int g2 = 0; g2 < RG; g2++) {
            a  += ls[g2 * C + threadIdx.x];
            a2 += ls2[g2 * C + threadIdx.x];
        }
        part[b * 2 * C + threadIdx.x] = a;
        part[b * 2 * C + C + threadIdx.x] = a2;
    }
}

template<int C>
__global__ __launch_bounds__(256) void bn_k(const float* __restrict__ pre,
                                            const float* __restrict__ part,
                                            const float* __restrict__ gm,
                                            const float* __restrict__ bt,
                                            unsigned short* __restrict__ act)
{
    __shared__ float sc[C], sh[C];
    if (threadIdx.x < C) {
        const int c = threadIdx.x;
        float s = 0.f, s2 = 0.f;
        for (int b = 0; b < 64; b++) {
            s  += part[b * 2 * C + c];
            s2 += part[b * 2 * C + C + c];
        }
        const float inv = 1.f / (float)NN;
        float mu = s * inv;
        float var = s2 * inv - mu * mu;
        float scale = gm[c] * rsqrtf(var + 1e-5f);
        sc[c] = scale;
        sh[c] = bt[c] - mu * scale;
    }
    __syncthreads();
    const int chunk = (NN + gridDim.x - 1) / gridDim.x;
    const int r0 = blockIdx.x * chunk;
    const int r1 = imin(NN, r0 + chunk);
    for (int i = r0 * C + threadIdx.x; i < r1 * C; i += 256) {
        const int c = i % C;
        float v = fmaxf(pre[i] * sc[c] + sh[c], 0.f);
        act[i] = f2bf(v);
    }
}

extern "C" void kernel_launch(void* const* d_in, const int* in_sizes, int n_in,
                              void* d_out, int out_size, void* d_ws, size_t ws_size,
                              hipStream_t stream) {
    const void* x    = d_in[0];
    const int*  idx  = (const int*)d_in[1];
    const void* wgt  = d_in[2];
    const void* W1   = d_in[3];
    const void* b1   = d_in[4];
    const void* g1   = d_in[5];
    const void* be1  = d_in[6];
    const void* W2   = d_in[7];
    const void* b2   = d_in[8];
    const void* g2   = d_in[9];
    const void* be2  = d_in[10];
    const void* W3   = d_in[11];
    const void* b3   = d_in[12];
    const void* g3   = d_in[13];
    const void* be3  = d_in[14];
    const void* Wout = d_in[15];
    const void* bout = d_in[16];

    char* ws = (char*)d_ws;
    size_t off = 0;
    auto alloc = [&](size_t bytes) {
        off = (off + 255) & ~(size_t)255;
        size_t o = off; off += bytes; return o;
    };
    const size_t o_flag  = alloc(4);
    const size_t o_xc    = alloc((size_t)NN * 3 * 2);
    const size_t o_wgtc  = alloc((size_t)NN * 75 * 4);
    const size_t o_W1c   = alloc(64 * 80 * 2);
    const size_t o_W2c   = alloc((size_t)64 * 1600 * 2);
    const size_t o_W3c   = alloc((size_t)128 * 1600 * 2);
    const size_t o_Woc   = alloc((size_t)48 * 3200 * 2);
    const size_t o_bias  = alloc(1024 * 4);
    const size_t o_pre   = alloc((size_t)NN * 128 * 4);
    const size_t o_actA  = alloc((size_t)NN * 128 * 2);
    const size_t o_actB  = alloc((size_t)NN * 64 * 2);
    const size_t o_part  = alloc((size_t)64 * 2 * 128 * 4);
    const size_t o_partial = alloc((size_t)2 * NN * 128 * 4);  // covers 4*NN*36 too
    if (ws_size < off) return;

    int* flag = (int*)(ws + o_flag);
    unsigned short* xc  = (unsigned short*)(ws + o_xc);
    float* wgtc = (float*)(ws + o_wgtc);
    unsigned short* W1c = (unsigned short*)(ws + o_W1c);
    unsigned short* W2c = (unsigned short*)(ws + o_W2c);
    unsigned short* W3c = (unsigned short*)(ws + o_W3c);
    unsigned short* Woc = (unsigned short*)(ws + o_Woc);
    float* biasc = (float*)(ws + o_bias);
    float* pre  = (float*)(ws + o_pre);
    unsigned short* actA = (unsigned short*)(ws + o_actA);
    unsigned short* actB = (unsigned short*)(ws + o_actB);
    float* part = (float*)(ws + o_part);
    float* partial = (float*)(ws + o_partial);

    detect_k<<<1, 64, 0, stream>>>(wgt, flag);

    Tab t;
    t.s[0]  = { x,    xc,        NN * 3,      NN * 3,     0 };
    t.s[1]  = { wgt,  wgtc,      NN * 75,     NN * 75,    1 };
    t.s[2]  = { W1,   W1c,       64 * 80,     64 * 80,    2 };
    t.s[3]  = { W2,   W2c,       64 * 1600,   64 * 1600,  0 };
    t.s[4]  = { W3,   W3c,       128 * 1600,  128 * 1600, 0 };
    t.s[5]  = { Wout, Woc,       48 * 3200,   36 * 3200,  0 };   // zero-pad rows 36..47
    t.s[6]  = { b1,   biasc + 0,   64, 64, 1 };
    t.s[7]  = { g1,   biasc + 64,  64, 64, 1 };
    t.s[8]  = { be1,  biasc + 128, 64, 64, 1 };
    t.s[9]  = { b2,   biasc + 192, 64, 64, 1 };
    t.s[10] = { g2,   biasc + 256, 64, 64, 1 };
    t.s[11] = { be2,  biasc + 320, 64, 64, 1 };
    t.s[12] = { b3,   biasc + 384, 128, 128, 1 };
    t.s[13] = { g3,   biasc + 512, 128, 128, 1 };
    t.s[14] = { be3,  biasc + 640, 128, 128, 1 };
    t.s[15] = { bout, biasc + 768, 36, 36, 1 };
    canon_k<<<dim3(768, 16), 256, 0, stream>>>(t, flag);

    dim3 B(256);
    // layer 1: 3 -> 64 (VALU, K=80)
    conv_k<3, 64, 64, 16><<<641, B, 0, stream>>>(xc, idx, wgtc, W1c, biasc + 0, pre);
    stats_k<64><<<64, B, 0, stream>>>(pre, part);
    bn_k<64><<<128, B, 0, stream>>>(pre, part, biasc + 64, biasc + 128, actA);
    // layer 2: 64 -> 64, split slots 13+12
    conv2_k<64, 64, 16, 4, 13><<<dim3(641, 2), B, 0, stream>>>(
        actA, idx, wgtc, W2c, partial, 12, 1, 64);
    reduce_stats_k<64, 2><<<64, B, 0, stream>>>(partial, biasc + 192, pre, part);
    bn_k<64><<<128, B, 0, stream>>>(pre, part, biasc + 256, biasc + 320, actB);
    // layer 3: 64 -> 128, split slots 13+12
    conv2_k<64, 128, 32, 4, 13><<<dim3(641, 2), B, 0, stream>>>(
        actB, idx, wgtc, W3c, partial, 12, 1, 128);
    reduce_stats_k<128, 2><<<64, B, 0, stream>>>(partial, biasc + 384, pre, part);
    bn_k<128><<<128, B, 0, stream>>>(pre, part, biasc + 512, biasc + 640, actA);
    // layer 4: 128 -> 36 (W padded to 48 rows), split slots 7+6+6+6
    conv2_k<128, 36, 16, 3, 7><<<dim3(641, 4), B, 0, stream>>>(
        actA, idx, wgtc, Woc, partial, 6, 1, 36);
    reduce_out_k<<<(NN * 36 + 255) / 256, B, 0, stream>>>(partial, biasc + 768, d_out, flag, 4);
}

// Round 6
// 213.991 us; speedup vs baseline: 1.0789x; 1.0789x over previous
//
#include <hip/hip_runtime.h>

#define NN 10242

typedef short s8v __attribute__((ext_vector_type(8)));
typedef float f32x4 __attribute__((ext_vector_type(4)));

static __device__ __forceinline__ float bf2f(unsigned short u) {
    unsigned int i = ((unsigned int)u) << 16;
    return __builtin_bit_cast(float, i);
}
static __device__ __forceinline__ unsigned short f2bf(float f) {
    unsigned int i = __builtin_bit_cast(unsigned int, f);
    unsigned int lsb = (i >> 16) & 1u;
    i += 0x7fffu + lsb;
    return (unsigned short)(i >> 16);
}
static __device__ __forceinline__ int imin(int a, int b) { return a < b ? a : b; }

// ---- dtype detector: neigh_weights rows (triples) sum to 1 in the true dtype ----
__global__ void detect_k(const void* __restrict__ wgt, int* __restrict__ flag) {
    const float* wf = (const float*)wgt;
    const int r = threadIdx.x;
    float s = wf[3 * r] + wf[3 * r + 1] + wf[3 * r + 2];
    bool ok = (s == s) && (fabsf(s - 1.f) < 0.05f);
    unsigned long long m = __ballot(ok);
    if (r == 0) *flag = (__popcll(m) >= 60) ? 1 : 0;
}

// ---- canonicalizer ----
// mode 0: ->bf16 (zero-fill i>=nsrc)  mode 1: ->f32  mode 2: W1 cols 75->80 ->bf16
// mode 3: W[cout][K] -> Wt[K/8][cpad][8] bf16 (zero rows cout..cpad-1)
struct Seg { const void* src; void* dst; int n; int nsrc; int mode; int K; int cout; int cpad; };
struct Tab { Seg s[16]; };

__global__ __launch_bounds__(256) void canon_k(Tab t, const int* __restrict__ flag) {
    const Seg sg = t.s[blockIdx.y];
    const bool f32src = (*flag != 0);
    for (int i = blockIdx.x * 256 + threadIdx.x; i < sg.n; i += gridDim.x * 256) {
        if (sg.mode == 0) {
            unsigned short v = 0;
            if (i < sg.nsrc)
                v = f32src ? f2bf(((const float*)sg.src)[i])
                           : ((const unsigned short*)sg.src)[i];
            ((unsigned short*)sg.dst)[i] = v;
        } else if (sg.mode == 1) {
            float v = f32src ? ((const float*)sg.src)[i]
                             : bf2f(((const unsigned short*)sg.src)[i]);
            ((float*)sg.dst)[i] = v;
        } else if (sg.mode == 2) {
            const int row = i / 80, col = i - row * 80;
            unsigned short v = 0;
            if (col < 75) {
                const int j = row * 75 + col;
                v = f32src ? f2bf(((const float*)sg.src)[j])
                           : ((const unsigned short*)sg.src)[j];
            }
            ((unsigned short*)sg.dst)[i] = v;
        } else {
            const int e = i & 7;
            const int r = i >> 3;
            const int c = r % sg.cpad;
            const int k8 = r / sg.cpad;
            unsigned short v = 0;
            if (c < sg.cout) {
                const int j = c * sg.K + k8 * 8 + e;
                v = f32src ? f2bf(((const float*)sg.src)[j])
                           : ((const unsigned short*)sg.src)[j];
            }
            ((unsigned short*)sg.dst)[i] = v;
        }
    }
}

// ---- layer-1 conv (K=80, VALU; cheap) ----
template<int CIN, int COUT, int CG, int NB>
__global__ __launch_bounds__(256) void conv_k(
    const unsigned short* __restrict__ X,
    const int* __restrict__ idx,
    const float* __restrict__ wgt,
    const unsigned short* __restrict__ W,    // [COUT][KPAD]
    const float* __restrict__ bias,
    float* __restrict__ Of)
{
    constexpr int K = 25 * CIN;
    constexpr int KPAD = (K + 7) & ~7;
    __shared__ unsigned short agg[NB][KPAD];
    const int tid = threadIdx.x;
    const int n0 = blockIdx.x * NB;

    for (int p = tid; p < NB * 25; p += 256) {
        const int r = p / 25;
        const int k = p - r * 25;
        const int n = n0 + r;
        if (n < NN) {
            const int base = n * 75 + k * 3;
            const int i0 = idx[base], i1 = idx[base + 1], i2 = idx[base + 2];
            const float w0 = wgt[base], w1 = wgt[base + 1], w2 = wgt[base + 2];
            for (int e = 0; e < CIN; e++) {
                float v = w0 * bf2f(X[i0 * CIN + e]) +
                          w1 * bf2f(X[i1 * CIN + e]) +
                          w2 * bf2f(X[i2 * CIN + e]);
                agg[r][k * CIN + e] = f2bf(v);
            }
        }
    }
    if constexpr (KPAD != K) {
        for (int p = tid; p < NB * (KPAD - K); p += 256) {
            const int r = p / (KPAD - K);
            agg[r][K + p - r * (KPAD - K)] = 0;
        }
    }
    __syncthreads();

    constexpr int RG = 256 / CG;
    constexpr int RPT = NB / RG;
    const int c = tid % CG;
    const int rq = tid / CG;
    float acc[RPT] = {};
    if (c < COUT) {
        const unsigned short* Wr = W + (size_t)c * KPAD;
        for (int j = 0; j < KPAD; j += 8) {
            s8v wv = *(const s8v*)(Wr + j);
            float wf[8];
            #pragma unroll
            for (int q = 0; q < 8; q++) wf[q] = bf2f((unsigned short)wv[q]);
            #pragma unroll
            for (int rr = 0; rr < RPT; rr++) {
                s8v av = *(const s8v*)(&agg[rq * RPT + rr][j]);
                #pragma unroll
                for (int q = 0; q < 8; q++)
                    acc[rr] += wf[q] * bf2f((unsigned short)av[q]);
            }
        }
        const float bb = bias[c];
        #pragma unroll
        for (int rr = 0; rr < RPT; rr++) {
            const int n = n0 + rq * RPT + rr;
            if (n < NN) Of[(size_t)n * COUT + c] = acc[rr] + bb;
        }
    }
}

// ---- fused gather+interp+MFMA conv: no A-tile LDS, static slot counts ----
// Wave (ng, cg): 16 nodes (n0blk + ng*16 ..) x cols [cg*NFRAG*16, ...).
// Lane (l15, kg): A-frag = interp of node (n0+l15), 8 channels at kg*8 within K-step.
template<int NS, int CIN, int COUT, int CPAD, int NFRAG, int NG>
static __device__ __forceinline__ void conv_body(
    int s0, int sy, int* iL, float* wL,
    const unsigned short* __restrict__ X,
    const int* __restrict__ idx,
    const float* __restrict__ wgt,
    const unsigned short* __restrict__ Wt,   // [K/8][CPAD][8]
    float* __restrict__ partial, int cstore)
{
    constexpr int NS3 = NS * 3;
    constexpr int NT = CIN / 32;             // K-steps per slot
    const int tid = threadIdx.x;
    const int n0blk = blockIdx.x * (NG * 16);

    // Stage 0: coalesced idx/wgt -> LDS
    for (int q = tid; q < NG * 16 * NS3; q += 256) {
        const int node = q / NS3;
        const int f = q - node * NS3;
        const int n = n0blk + node;
        const bool ok = n < NN;
        const int g = ok ? (n * 75 + s0 * 3 + f) : 0;
        iL[q] = idx[g];
        wL[q] = ok ? wgt[g] : 0.f;
    }
    __syncthreads();

    const int wv = tid >> 6;
    const int lane = tid & 63;
    const int ng = wv & (NG - 1);
    const int cg = wv / NG;
    const int n0 = n0blk + ng * 16;
    const int colbase = cg * NFRAG * 16;
    const int l15 = lane & 15;
    const int kg = lane >> 4;
    const int ibase = (ng * 16 + l15) * NS3;

    f32x4 acc[NFRAG] = {};

    #pragma unroll 2
    for (int s = 0; s < NS; s++) {
        const int i0 = iL[ibase + s * 3];
        const int i1 = iL[ibase + s * 3 + 1];
        const int i2 = iL[ibase + s * 3 + 2];
        const float w0 = wL[ibase + s * 3];
        const float w1 = wL[ibase + s * 3 + 1];
        const float w2 = wL[ibase + s * 3 + 2];
        const unsigned short* x0 = X + (size_t)i0 * CIN + kg * 8;
        const unsigned short* x1 = X + (size_t)i1 * CIN + kg * 8;
        const unsigned short* x2 = X + (size_t)i2 * CIN + kg * 8;
        const unsigned short* wp = Wt +
            ((size_t)((s0 + s) * (CIN / 8) + kg) * CPAD + colbase + l15) * 8;
        #pragma unroll
        for (int t = 0; t < NT; t++) {
            const s8v va = *(const s8v*)(x0 + t * 32);
            const s8v vb = *(const s8v*)(x1 + t * 32);
            const s8v vc = *(const s8v*)(x2 + t * 32);
            s8v a;
            #pragma unroll
            for (int q = 0; q < 8; q++)
                a[q] = (short)f2bf(w0 * bf2f((unsigned short)va[q]) +
                                   w1 * bf2f((unsigned short)vb[q]) +
                                   w2 * bf2f((unsigned short)vc[q]));
            const unsigned short* wpt = wp + (size_t)(t * 4) * CPAD * 8;
            #pragma unroll
            for (int j = 0; j < NFRAG; j++) {
                const s8v b = *(const s8v*)(wpt + j * 16 * 8);
                acc[j] = __builtin_amdgcn_mfma_f32_16x16x32_bf16(a, b, acc[j], 0, 0, 0);
            }
        }
    }

    #pragma unroll
    for (int j = 0; j < NFRAG; j++) {
        const int col = colbase + j * 16 + l15;
        if (col < COUT) {
            #pragma unroll
            for (int q = 0; q < 4; q++) {
                const int n = n0 + kg * 4 + q;   // C row = (lane>>4)*4 + reg
                if (n < NN)
                    partial[((size_t)sy * NN + n) * cstore + col] = acc[j][q];
            }
        }
    }
}

template<int CIN, int COUT, int CPAD, int NFRAG, int NG, int NSA, int NSB>
__global__ __launch_bounds__(256, 4) void conv_f(
    const unsigned short* __restrict__ X,
    const int* __restrict__ idx,
    const float* __restrict__ wgt,
    const unsigned short* __restrict__ Wt,
    float* __restrict__ partial, int cstore)
{
    __shared__ int   iL[NG * 16 * NSA * 3];
    __shared__ float wL[NG * 16 * NSA * 3];
    const int sy = blockIdx.y;
    if (sy == 0)
        conv_body<NSA, CIN, COUT, CPAD, NFRAG, NG>(0, 0, iL, wL, X, idx, wgt, Wt, partial, cstore);
    else
        conv_body<NSB, CIN, COUT, CPAD, NFRAG, NG>(NSA + (sy - 1) * NSB, sy, iL, wL, X, idx, wgt, Wt, partial, cstore);
}

// ---- fused: pre = sum(partials)+bias; column stats partials ----
template<int C, int S>
__global__ __launch_bounds__(256) void reduce_stats_k(
    const float* __restrict__ partial,
    const float* __restrict__ bias,
    float* __restrict__ pre,
    float* __restrict__ part)
{
    constexpr int RG = 256 / C;
    constexpr int CH = (NN + 63) / 64;
    const int b = blockIdx.x;
    const int r0 = b * CH;
    const int r1 = imin(NN, r0 + CH);
    const int c = threadIdx.x % C;
    const int g = threadIdx.x / C;
    const float bb = bias[c];
    float s = 0.f, s2 = 0.f;
    for (int r = r0 + g; r < r1; r += RG) {
        float v = bb;
        #pragma unroll
        for (int si = 0; si < S; si++)
            v += partial[((size_t)si * NN + r) * C + c];
        pre[(size_t)r * C + c] = v;
        s += v; s2 += v * v;
    }
    __shared__ float ls[256], ls2[256];
    ls[threadIdx.x] = s; ls2[threadIdx.x] = s2;
    __syncthreads();
    if (threadIdx.x < C) {
        float a = 0.f, a2 = 0.f;
        #pragma unroll
        for (int g2 = 0; g2 < RG; g2++) {
            a  += ls[g2 * C + threadIdx.x];
            a2 += ls2[g2 * C + threadIdx.x];
        }
        part[b * 2 * C + threadIdx.x] = a;
        part[b * 2 * C + C + threadIdx.x] = a2;
    }
}

// ---- final: out = sum(partials)+bias, store in detected dtype ----
__global__ __launch_bounds__(256) void reduce_out_k(
    const float* __restrict__ partial,
    const float* __restrict__ bias,
    void* __restrict__ Ob,
    const int* __restrict__ flag, int S)
{
    const int i = blockIdx.x * 256 + threadIdx.x;
    if (i >= NN * 36) return;
    const int c = i % 36;
    float v = bias[c];
    for (int si = 0; si < S; si++)
        v += partial[(size_t)si * NN * 36 + i];
    if (*flag) ((float*)Ob)[i] = v;
    else       ((unsigned short*)Ob)[i] = f2bf(v);
}

template<int C>
__global__ __launch_bounds__(256) void stats_k(const float* __restrict__ pre,
                                               float* __restrict__ part)
{
    constexpr int RG = 256 / C;
    constexpr int CH = (NN + 63) / 64;
    const int b = blockIdx.x;
    const int r0 = b * CH;
    const int r1 = imin(NN, r0 + CH);
    const int c = threadIdx.x % C;
    const int g = threadIdx.x / C;
    float s = 0.f, s2 = 0.f;
    for (int r = r0 + g; r < r1; r += RG) {
        float v = pre[(size_t)r * C + c];
        s += v; s2 += v * v;
    }
    __shared__ float ls[256], ls2[256];
    ls[threadIdx.x] = s; ls2[threadIdx.x] = s2;
    __syncthreads();
    if (threadIdx.x < C) {
        float a = 0.f, a2 = 0.f;
        #pragma unroll
        for (int g2 = 0; g2 < RG; g2++) {
            a  += ls[g2 * C + threadIdx.x];
            a2 += ls2[g2 * C + threadIdx.x];
        }
        part[b * 2 * C + threadIdx.x] = a;
        part[b * 2 * C + C + threadIdx.x] = a2;
    }
}

template<int C>
__global__ __launch_bounds__(256) void bn_k(const float* __restrict__ pre,
                                            const float* __restrict__ part,
                                            const float* __restrict__ gm,
                                            const float* __restrict__ bt,
                                            unsigned short* __restrict__ act)
{
    __shared__ float sc[C], sh[C];
    if (threadIdx.x < C) {
        const int c = threadIdx.x;
        float s = 0.f, s2 = 0.f;
        for (int b = 0; b < 64; b++) {
            s  += part[b * 2 * C + c];
            s2 += part[b * 2 * C + C + c];
        }
        const float inv = 1.f / (float)NN;
        float mu = s * inv;
        float var = s2 * inv - mu * mu;
        float scale = gm[c] * rsqrtf(var + 1e-5f);
        sc[c] = scale;
        sh[c] = bt[c] - mu * scale;
    }
    __syncthreads();
    const int chunk = (NN + gridDim.x - 1) / gridDim.x;
    const int r0 = blockIdx.x * chunk;
    const int r1 = imin(NN, r0 + chunk);
    for (int i = r0 * C + threadIdx.x; i < r1 * C; i += 256) {
        const int c = i % C;
        float v = fmaxf(pre[i] * sc[c] + sh[c], 0.f);
        act[i] = f2bf(v);
    }
}

extern "C" void kernel_launch(void* const* d_in, const int* in_sizes, int n_in,
                              void* d_out, int out_size, void* d_ws, size_t ws_size,
                              hipStream_t stream) {
    const void* x    = d_in[0];
    const int*  idx  = (const int*)d_in[1];
    const void* wgt  = d_in[2];
    const void* W1   = d_in[3];
    const void* b1   = d_in[4];
    const void* g1   = d_in[5];
    const void* be1  = d_in[6];
    const void* W2   = d_in[7];
    const void* b2   = d_in[8];
    const void* g2   = d_in[9];
    const void* be2  = d_in[10];
    const void* W3   = d_in[11];
    const void* b3   = d_in[12];
    const void* g3   = d_in[13];
    const void* be3  = d_in[14];
    const void* Wout = d_in[15];
    const void* bout = d_in[16];

    char* ws = (char*)d_ws;
    size_t off = 0;
    auto alloc = [&](size_t bytes) {
        off = (off + 255) & ~(size_t)255;
        size_t o = off; off += bytes; return o;
    };
    const size_t o_flag  = alloc(4);
    const size_t o_xc    = alloc((size_t)NN * 3 * 2);
    const size_t o_wgtc  = alloc((size_t)NN * 75 * 4);
    const size_t o_W1c   = alloc(64 * 80 * 2);
    const size_t o_Wt2   = alloc((size_t)200 * 64 * 8 * 2);    // [K/8][64][8]
    const size_t o_Wt3   = alloc((size_t)200 * 128 * 8 * 2);   // [K/8][128][8]
    const size_t o_Wt4   = alloc((size_t)400 * 48 * 8 * 2);    // [K/8][48][8]
    const size_t o_bias  = alloc(1024 * 4);
    const size_t o_pre   = alloc((size_t)NN * 128 * 4);
    const size_t o_actA  = alloc((size_t)NN * 128 * 2);
    const size_t o_actB  = alloc((size_t)NN * 64 * 2);
    const size_t o_part  = alloc((size_t)64 * 2 * 128 * 4);
    const size_t o_partial = alloc((size_t)2 * NN * 128 * 4);  // covers 4*NN*36 too
    if (ws_size < off) return;

    int* flag = (int*)(ws + o_flag);
    unsigned short* xc  = (unsigned short*)(ws + o_xc);
    float* wgtc = (float*)(ws + o_wgtc);
    unsigned short* W1c = (unsigned short*)(ws + o_W1c);
    unsigned short* Wt2 = (unsigned short*)(ws + o_Wt2);
    unsigned short* Wt3 = (unsigned short*)(ws + o_Wt3);
    unsigned short* Wt4 = (unsigned short*)(ws + o_Wt4);
    float* biasc = (float*)(ws + o_bias);
    float* pre  = (float*)(ws + o_pre);
    unsigned short* actA = (unsigned short*)(ws + o_actA);
    unsigned short* actB = (unsigned short*)(ws + o_actB);
    float* part = (float*)(ws + o_part);
    float* partial = (float*)(ws + o_partial);

    detect_k<<<1, 64, 0, stream>>>(wgt, flag);

    Tab t;
    t.s[0]  = { x,    xc,   NN * 3,          NN * 3,  0, 0, 0, 0 };
    t.s[1]  = { wgt,  wgtc, NN * 75,         NN * 75, 1, 0, 0, 0 };
    t.s[2]  = { W1,   W1c,  64 * 80,         64 * 80, 2, 0, 0, 0 };
    t.s[3]  = { W2,   Wt2,  200 * 64 * 8,    0,       3, 1600, 64, 64 };
    t.s[4]  = { W3,   Wt3,  200 * 128 * 8,   0,       3, 1600, 128, 128 };
    t.s[5]  = { Wout, Wt4,  400 * 48 * 8,    0,       3, 3200, 36, 48 };
    t.s[6]  = { b1,   biasc + 0,   64, 64, 1, 0, 0, 0 };
    t.s[7]  = { g1,   biasc + 64,  64, 64, 1, 0, 0, 0 };
    t.s[8]  = { be1,  biasc + 128, 64, 64, 1, 0, 0, 0 };
    t.s[9]  = { b2,   biasc + 192, 64, 64, 1, 0, 0, 0 };
    t.s[10] = { g2,   biasc + 256, 64, 64, 1, 0, 0, 0 };
    t.s[11] = { be2,  biasc + 320, 64, 64, 1, 0, 0, 0 };
    t.s[12] = { b3,   biasc + 384, 128, 128, 1, 0, 0, 0 };
    t.s[13] = { g3,   biasc + 512, 128, 128, 1, 0, 0, 0 };
    t.s[14] = { be3,  biasc + 640, 128, 128, 1, 0, 0, 0 };
    t.s[15] = { bout, biasc + 768, 36, 36, 1, 0, 0, 0 };
    canon_k<<<dim3(768, 16), 256, 0, stream>>>(t, flag);

    dim3 B(256);
    // layer 1: 3 -> 64 (VALU, K=80)
    conv_k<3, 64, 64, 16><<<641, B, 0, stream>>>(xc, idx, wgtc, W1c, biasc + 0, pre);
    stats_k<64><<<64, B, 0, stream>>>(pre, part);
    bn_k<64><<<128, B, 0, stream>>>(pre, part, biasc + 64, biasc + 128, actA);
    // layer 2: 64 -> 64 fused MFMA; NG=2 nodes-groups, 2 col-groups x NFRAG=2; S=2 (13+12)
    conv_f<64, 64, 64, 2, 2, 13, 12><<<dim3(321, 2), B, 0, stream>>>(
        actA, idx, wgtc, Wt2, partial, 64);
    reduce_stats_k<64, 2><<<64, B, 0, stream>>>(partial, biasc + 192, pre, part);
    bn_k<64><<<128, B, 0, stream>>>(pre, part, biasc + 256, biasc + 320, actB);
    // layer 3: 64 -> 128; NG=2, 2 col-groups x NFRAG=4; S=2 (13+12)
    conv_f<64, 128, 128, 4, 2, 13, 12><<<dim3(321, 2), B, 0, stream>>>(
        actB, idx, wgtc, Wt3, partial, 128);
    reduce_stats_k<128, 2><<<64, B, 0, stream>>>(partial, biasc + 384, pre, part);
    bn_k<128><<<128, B, 0, stream>>>(pre, part, biasc + 512, biasc + 640, actA);
    // layer 4: 128 -> 36 (pad 48); NG=4, 1 col-group x NFRAG=3; S=4 (7+6+6+6)
    conv_f<128, 36, 48, 3, 4, 7, 6><<<dim3(161, 4), B, 0, stream>>>(
        actA, idx, wgtc, Wt4, partial, 36);
    reduce_out_k<<<(NN * 36 + 255) / 256, B, 0, stream>>>(partial, biasc + 768, d_out, flag, 4);
}